// Round 10
// baseline (354.157 us; speedup 1.0000x reference)
//
#include <hip/hip_runtime.h>
#include <hip/hip_bf16.h>
#include <stdint.h>

#define NN 50000
#define NE 800000

typedef unsigned short ushort8 __attribute__((ext_vector_type(8)));
typedef __bf16 bf16x8 __attribute__((ext_vector_type(8)));
typedef float f32x4 __attribute__((ext_vector_type(4)));

// ---------- dtype helpers ----------
__device__ __forceinline__ float bf2f_bits(unsigned short u) {
  unsigned int x = ((unsigned int)u) << 16;
  float f;
  __builtin_memcpy(&f, &x, 4);
  return f;
}
__device__ __forceinline__ unsigned short f2bf_bits(float f) {
  unsigned int x;
  __builtin_memcpy(&x, &f, 4);
  unsigned int lsb = (x >> 16) & 1u;
  x += 0x7fffu + lsb;                       // round to nearest even
  return (unsigned short)(x >> 16);
}
__device__ __forceinline__ float lo16(unsigned int v) { return bf2f_bits((unsigned short)v); }
__device__ __forceinline__ float hi16(unsigned int v) { return bf2f_bits((unsigned short)(v >> 16)); }
__device__ __forceinline__ float loadf(const void* base, size_t idx, int isbf) {
  if (isbf) return bf2f_bits(((const unsigned short*)base)[idx]);
  return ((const float*)base)[idx];
}

// ---------- dtype sniff (block 0) + cnt zeroing (all blocks) ----------
__global__ void k_sniff(const void* x, const void* ei, int* flags, int* cnt) {
  int i = blockIdx.x * 256 + threadIdx.x;
  if (i < NN) cnt[i] = 0;
  if (blockIdx.x != 0) return;
  __shared__ int badbf;
  __shared__ int zodd;
  int tid = threadIdx.x;
  if (tid == 0) { badbf = 0; zodd = 0; }
  __syncthreads();
  unsigned short u = ((const unsigned short*)x)[tid];
  float v = bf2f_bits(u);
  float av = fabsf(v);
  int ok = (av == 0.0f) || (av > 1e-8f && av < 1e8f);
  if (!ok) atomicAdd(&badbf, 1);
  int e32 = ((const int*)ei)[tid];
  if ((tid & 1) && e32 == 0) atomicAdd(&zodd, 1);
  __syncthreads();
  if (tid == 0) {
    flags[0] = (badbf <= 12) ? 1 : 0;
    flags[1] = (zodd >= 100) ? 1 : 0;
  }
}

// convert edges + degree-count + per-edge rank in ONE atomic pass
// (50k counters -> ~16 atomics/address: low contention [R5]; few-counter
//  schemes serialize: R6's 391-counter variant cost 282us.
//  R9's XCD-partitioned fill was net-negative: reverted.)
__global__ void k_cvt_edges(const void* ei, int* erow, int* ecol, int* rank,
                            int* cnt, const int* flags) {
  int e = blockIdx.x * 256 + threadIdx.x;
  if (e >= NE) return;
  int r, c;
  if (flags[1]) {
    const long long* p = (const long long*)ei;
    r = (int)p[e];
    c = (int)p[NE + e];
  } else {
    const int* p = (const int*)ei;
    r = p[e];
    c = p[NE + e];
  }
  erow[e] = r;
  ecol[e] = c;
  rank[e] = atomicAdd(&cnt[c], 1);
}

// x (fp32) -> bf16 internal; no-op when device tensors already bf16
__global__ void k_cvt_xb(const void* x, unsigned short* xb, const int* flags) {
  if (flags[0]) return;
  int i4 = (blockIdx.x * 256 + threadIdx.x) * 4;
  if (i4 >= NN * 128) return;
  float4 v = *reinterpret_cast<const float4*>((const float*)x + i4);
  xb[i4 + 0] = f2bf_bits(v.x); xb[i4 + 1] = f2bf_bits(v.y);
  xb[i4 + 2] = f2bf_bits(v.z); xb[i4 + 3] = f2bf_bits(v.w);
}

// ---------- degree / CSR ----------
__global__ void k_scan1(const int* cnt, int* indptr, int* bsum, float* dinv, int n) {
  __shared__ int sm[256];
  int tid = threadIdx.x;
  int i = blockIdx.x * 256 + tid;
  int v = (i < n) ? cnt[i] : 0;
  if (i < n) dinv[i] = rsqrtf((float)(v + 1));   // +1 self loop
  sm[tid] = v;
  __syncthreads();
  for (int off = 1; off < 256; off <<= 1) {
    int t = (tid >= off) ? sm[tid - off] : 0;
    __syncthreads();
    sm[tid] += t;
    __syncthreads();
  }
  if (i < n) indptr[i] = sm[tid] - v;
  if (tid == 255) bsum[blockIdx.x] = sm[255];
}
__global__ void k_scan2(int* bsum, int nb) {
  __shared__ int sm[256];
  int tid = threadIdx.x;
  int v = (tid < nb) ? bsum[tid] : 0;
  sm[tid] = v;
  __syncthreads();
  for (int off = 1; off < 256; off <<= 1) {
    int t = (tid >= off) ? sm[tid - off] : 0;
    __syncthreads();
    sm[tid] += t;
    __syncthreads();
  }
  if (tid < nb) bsum[tid] = sm[tid] - v;
  if (tid == 0) bsum[nb] = sm[255];
}
__global__ void k_scan3(int* indptr, const int* bsum, int n, int nb) {
  int i = blockIdx.x * 256 + threadIdx.x;
  if (i < n) indptr[i] += bsum[i >> 8];
  else if (i == n) indptr[n] = bsum[nb];
}
// atomic-free fill (R8 version: measured best)
__global__ void k_fill(const int* erow, const int* ecol, const int* rank,
                       const int* indptr, int* srcs) {
  int e = blockIdx.x * 256 + threadIdx.x;
  if (e >= NE) return;
  srcs[indptr[ecol[e]] + rank[e]] = erow[e];
}

// ---------- BN folding (all 4 layers fused) ----------
__global__ void k_prep_wt_all(
    const void* W1, const void* Wc0, const void* Wc1, const void* Wout,
    const void* g1, const void* g2, const void* g3, const void* g4,
    const void* rv1, const void* rv2, const void* rv3, const void* rv4,
    unsigned short* Wtb, const int* flags) {
  int idx = blockIdx.x * 256 + threadIdx.x;
  if (idx >= 90112) return;
  int isbf = flags[0];
  const void *W, *g, *rv;
  int K, NOUT, base;
  if (idx < 16384)      { W = W1;   g = g1; rv = rv1; K = 128; NOUT = 128; base = 0; }
  else if (idx < 32768) { W = Wc0;  g = g2; rv = rv2; K = 128; NOUT = 128; base = 16384; }
  else if (idx < 65536) { W = Wc1;  g = g3; rv = rv3; K = 256; NOUT = 128; base = 32768; }
  else                  { W = Wout; g = g4; rv = rv4; K = 384; NOUT = 64;  base = 65536; }
  int li = idx - base;
  int j = li / K, k = li % K;
  float s = loadf(g, k, isbf) * rsqrtf(loadf(rv, k, isbf) + 1e-5f);
  Wtb[idx] = f2bf_bits(s * loadf(W, (size_t)k * NOUT + j, isbf));
}
__global__ void k_prep_c_all(
    const void* W1, const void* Wc0, const void* Wc1, const void* Wout,
    const void* g1, const void* g2, const void* g3, const void* g4,
    const void* b1, const void* b2, const void* b3, const void* b4,
    const void* rm1, const void* rm2, const void* rm3, const void* rm4,
    const void* rv1, const void* rv2, const void* rv3, const void* rv4,
    float* cvec, const int* flags) {
  int jj = blockIdx.x;        // 0..447
  int lane = threadIdx.x;
  int isbf = flags[0];
  const void *W, *g, *bb, *rm, *rv;
  int K, NOUT, j;
  if (jj < 128)      { W = W1;   g = g1; bb = b1; rm = rm1; rv = rv1; K = 128; NOUT = 128; j = jj; }
  else if (jj < 256) { W = Wc0;  g = g2; bb = b2; rm = rm2; rv = rv2; K = 128; NOUT = 128; j = jj - 128; }
  else if (jj < 384) { W = Wc1;  g = g3; bb = b3; rm = rm3; rv = rv3; K = 256; NOUT = 128; j = jj - 256; }
  else               { W = Wout; g = g4; bb = b4; rm = rm4; rv = rv4; K = 384; NOUT = 64;  j = jj - 384; }
  float acc = 0.f;
  for (int k = lane; k < K; k += 64) {
    float s = loadf(g, k, isbf) * rsqrtf(loadf(rv, k, isbf) + 1e-5f);
    float t = loadf(bb, k, isbf) - loadf(rm, k, isbf) * s;
    acc += t * loadf(W, (size_t)k * NOUT + j, isbf);
  }
#pragma unroll
  for (int off = 32; off; off >>= 1) acc += __shfl_down(acc, off);
  if (lane == 0) cvec[jj] = acc;
}

// ---------- MFMA GEMM; A source selected at runtime (bf16: d_out/x direct) ----
template <int NOUT, int K>
__global__ __launch_bounds__(256) void k_gemm_mfma(
    const unsigned short* __restrict__ h0b, const unsigned short* __restrict__ h1b,
    const unsigned short* __restrict__ h2b,
    const unsigned short* __restrict__ h0d, const unsigned short* __restrict__ h1d,
    const unsigned short* __restrict__ h2d,
    const unsigned short* __restrict__ Wtb,
    const float* __restrict__ cvec, const float* __restrict__ dinv,
    unsigned short* __restrict__ hb, const int* __restrict__ flags) {
  constexpr int KS = K / 32;
  constexpr int NT = NOUT / 16;
  int isbf = flags[0];
  const unsigned short* h0 = (isbf && h0d) ? h0d : h0b;
  const unsigned short* h1 = (isbf && h1d) ? h1d : h1b;
  const unsigned short* h2 = (isbf && h2d) ? h2d : h2b;
  int tid = threadIdx.x;
  int wv = tid >> 6, lane = tid & 63;
  int row0 = blockIdx.x * 64 + wv * 16;
  int l15 = lane & 15;
  int kq = lane >> 4;
  int arow = row0 + l15;
  bool inb = arow < NN;

  bf16x8 afrag[KS];
#pragma unroll
  for (int ks = 0; ks < KS; ++ks) {
    int kg = ks * 32 + kq * 8;
    const unsigned short* src = (kg >> 7) == 0 ? h0 : ((kg >> 7) == 1 ? h1 : h2);
    ushort8 u = (ushort8)0;
    if (inb) u = *reinterpret_cast<const ushort8*>(src + (size_t)arow * 128 + (kg & 127));
    afrag[ks] = __builtin_bit_cast(bf16x8, u);
  }

  f32x4 acc[NT];
#pragma unroll
  for (int nt = 0; nt < NT; ++nt) acc[nt] = (f32x4)0.f;

#pragma unroll
  for (int nt = 0; nt < NT; ++nt) {
    const unsigned short* wrow = Wtb + (size_t)(nt * 16 + l15) * K + kq * 8;
#pragma unroll
    for (int ks = 0; ks < KS; ++ks) {
      ushort8 u = *reinterpret_cast<const ushort8*>(wrow + ks * 32);
      acc[nt] = __builtin_amdgcn_mfma_f32_16x16x32_bf16(
          afrag[ks], __builtin_bit_cast(bf16x8, u), acc[nt], 0, 0, 0);
    }
  }

  int orow0 = row0 + kq * 4;
  float dv[4];
  bool ob[4];
#pragma unroll
  for (int r = 0; r < 4; ++r) {
    int orow = orow0 + r;
    ob[r] = orow < NN;
    dv[r] = ob[r] ? dinv[orow] : 0.f;
  }
#pragma unroll
  for (int nt = 0; nt < NT; ++nt) {
    int col = nt * 16 + l15;
    float cv = cvec[col];
#pragma unroll
    for (int r = 0; r < 4; ++r) {
      if (ob[r])
        hb[(size_t)(orow0 + r) * NOUT + col] = f2bf_bits(dv[r] * (acc[nt][r] + cv));
    }
  }
}

// ---------- aggregation (128-wide): one wave/node, 2 edges per load batch ----
// Half-wave h=lane>>5 owns alternate edges; lane covers features
// [4*(lane&31) .. +3] via one uint2 (8B). 8-deep unroll => 16 edges in flight.
// Cross-half __shfl_xor(32) combines partials; self/odd-tail in half 0 only.
template <bool RELU>
__global__ __launch_bounds__(256) void k_agg128(
    const unsigned short* __restrict__ hb, const int* __restrict__ indptr,
    const int* __restrict__ srcs, const float* __restrict__ dinv,
    const void* __restrict__ bias, void* __restrict__ dout, size_t region_off,
    unsigned short* __restrict__ rb, const int* __restrict__ flags) {
  int gw = __builtin_amdgcn_readfirstlane(blockIdx.x * 4 + (threadIdx.x >> 6));
  int lane = threadIdx.x & 63;
  if (gw >= NN) return;
  int isbf = flags[0];
  int h = lane >> 5;
  int sl = lane & 31;
  size_t co = (size_t)sl * 4;                 // 4 bf16 = one uint2
  int e0 = indptr[gw], e1 = indptr[gw + 1];

  float a0 = 0.f, a1 = 0.f, a2 = 0.f, a3 = 0.f;
  float b0 = 0.f, b1 = 0.f, b2 = 0.f, b3 = 0.f;
  float c0 = 0.f, c1 = 0.f, c2 = 0.f, c3 = 0.f;
  float d0 = 0.f, d1 = 0.f, d2 = 0.f, d3 = 0.f;
  if (h == 0) {                                // self row once
    uint2 sv = *reinterpret_cast<const uint2*>(hb + (size_t)gw * 128 + co);
    a0 = lo16(sv.x); a1 = hi16(sv.x); a2 = lo16(sv.y); a3 = hi16(sv.y);
  }
  int e = e0;
  for (; e + 15 < e1; e += 16) {               // 16 edges in flight per wave
    int s0 = srcs[e + 0 + h],  s1 = srcs[e + 2 + h];
    int s2 = srcs[e + 4 + h],  s3 = srcs[e + 6 + h];
    int s4 = srcs[e + 8 + h],  s5 = srcs[e + 10 + h];
    int s6 = srcs[e + 12 + h], s7 = srcs[e + 14 + h];
    uint2 v0 = *reinterpret_cast<const uint2*>(hb + (size_t)s0 * 128 + co);
    uint2 v1 = *reinterpret_cast<const uint2*>(hb + (size_t)s1 * 128 + co);
    uint2 v2 = *reinterpret_cast<const uint2*>(hb + (size_t)s2 * 128 + co);
    uint2 v3 = *reinterpret_cast<const uint2*>(hb + (size_t)s3 * 128 + co);
    uint2 v4 = *reinterpret_cast<const uint2*>(hb + (size_t)s4 * 128 + co);
    uint2 v5 = *reinterpret_cast<const uint2*>(hb + (size_t)s5 * 128 + co);
    uint2 v6 = *reinterpret_cast<const uint2*>(hb + (size_t)s6 * 128 + co);
    uint2 v7 = *reinterpret_cast<const uint2*>(hb + (size_t)s7 * 128 + co);
    a0 += lo16(v0.x); a1 += hi16(v0.x); a2 += lo16(v0.y); a3 += hi16(v0.y);
    b0 += lo16(v1.x); b1 += hi16(v1.x); b2 += lo16(v1.y); b3 += hi16(v1.y);
    c0 += lo16(v2.x); c1 += hi16(v2.x); c2 += lo16(v2.y); c3 += hi16(v2.y);
    d0 += lo16(v3.x); d1 += hi16(v3.x); d2 += lo16(v3.y); d3 += hi16(v3.y);
    a0 += lo16(v4.x); a1 += hi16(v4.x); a2 += lo16(v4.y); a3 += hi16(v4.y);
    b0 += lo16(v5.x); b1 += hi16(v5.x); b2 += lo16(v5.y); b3 += hi16(v5.y);
    c0 += lo16(v6.x); c1 += hi16(v6.x); c2 += lo16(v6.y); c3 += hi16(v6.y);
    d0 += lo16(v7.x); d1 += hi16(v7.x); d2 += lo16(v7.y); d3 += hi16(v7.y);
  }
  for (; e + 1 < e1; e += 2) {                 // 2-at-a-time remainder
    int s0 = srcs[e + h];
    uint2 v0 = *reinterpret_cast<const uint2*>(hb + (size_t)s0 * 128 + co);
    a0 += lo16(v0.x); a1 += hi16(v0.x); a2 += lo16(v0.y); a3 += hi16(v0.y);
  }
  if (e < e1 && h == 0) {                      // odd tail
    int s0 = srcs[e];
    uint2 v0 = *reinterpret_cast<const uint2*>(hb + (size_t)s0 * 128 + co);
    a0 += lo16(v0.x); a1 += hi16(v0.x); a2 += lo16(v0.y); a3 += hi16(v0.y);
  }
  float t0 = (a0 + b0) + (c0 + d0);
  float t1 = (a1 + b1) + (c1 + d1);
  float t2 = (a2 + b2) + (c2 + d2);
  float t3 = (a3 + b3) + (c3 + d3);
  t0 += __shfl_xor(t0, 32);                    // combine half-waves
  t1 += __shfl_xor(t1, 32);
  t2 += __shfl_xor(t2, 32);
  t3 += __shfl_xor(t3, 32);
  if (h != 0) return;
  float dv = dinv[gw];
  float o0 = dv * t0 + loadf(bias, co + 0, isbf);
  float o1 = dv * t1 + loadf(bias, co + 1, isbf);
  float o2 = dv * t2 + loadf(bias, co + 2, isbf);
  float o3 = dv * t3 + loadf(bias, co + 3, isbf);
  if (RELU) {
    o0 = fmaxf(o0, 0.f); o1 = fmaxf(o1, 0.f);
    o2 = fmaxf(o2, 0.f); o3 = fmaxf(o3, 0.f);
  }
  size_t eo = region_off + (size_t)gw * 128 + co;
  uint2 pk;
  pk.x = (unsigned int)f2bf_bits(o0) | ((unsigned int)f2bf_bits(o1) << 16);
  pk.y = (unsigned int)f2bf_bits(o2) | ((unsigned int)f2bf_bits(o3) << 16);
  if (isbf) {
    // d_out region doubles as the residual buffer (read by next GEMM)
    *reinterpret_cast<uint2*>((unsigned short*)dout + eo) = pk;
  } else {
    float4 fo; fo.x = o0; fo.y = o1; fo.z = o2; fo.w = o3;
    *reinterpret_cast<float4*>((float*)dout + eo) = fo;
    *reinterpret_cast<uint2*>(rb + (size_t)gw * 128 + co) = pk;
  }
}

// ---------- aggregation (64-wide final layer): 32 lanes/node ----------
__global__ __launch_bounds__(256) void k_agg64out(
    const unsigned short* __restrict__ hb, const int* __restrict__ indptr,
    const int* __restrict__ srcs, const float* __restrict__ dinv,
    const void* __restrict__ bias, void* __restrict__ dout,
    const int* __restrict__ flags) {
  int gw = blockIdx.x * 8 + (threadIdx.x >> 5);
  int lane = threadIdx.x & 31;
  if (gw >= NN) return;
  int isbf = flags[0];
  int e0 = indptr[gw], e1 = indptr[gw + 1];
  int e = e0;
  size_t co = (size_t)lane * 2;
  unsigned int sv = *reinterpret_cast<const unsigned int*>(hb + (size_t)gw * 64 + co);
  float a0 = lo16(sv), a1 = hi16(sv);
  float b0 = 0.f, b1 = 0.f, c0 = 0.f, c1 = 0.f, d0 = 0.f, d1 = 0.f;
  for (; e + 3 < e1; e += 4) {
    int sa = srcs[e], sb = srcs[e + 1], sc = srcs[e + 2], sd = srcs[e + 3];
    unsigned int va = *reinterpret_cast<const unsigned int*>(hb + (size_t)sa * 64 + co);
    unsigned int vb = *reinterpret_cast<const unsigned int*>(hb + (size_t)sb * 64 + co);
    unsigned int vc = *reinterpret_cast<const unsigned int*>(hb + (size_t)sc * 64 + co);
    unsigned int vd = *reinterpret_cast<const unsigned int*>(hb + (size_t)sd * 64 + co);
    a0 += lo16(va); a1 += hi16(va); b0 += lo16(vb); b1 += hi16(vb);
    c0 += lo16(vc); c1 += hi16(vc); d0 += lo16(vd); d1 += hi16(vd);
  }
  for (; e < e1; ++e) {
    int sa = srcs[e];
    unsigned int va = *reinterpret_cast<const unsigned int*>(hb + (size_t)sa * 64 + co);
    a0 += lo16(va); a1 += hi16(va);
  }
  float dv = dinv[gw];
  float o0 = dv * ((a0 + b0) + (c0 + d0)) + loadf(bias, co + 0, isbf);
  float o1 = dv * ((a1 + b1) + (c1 + d1)) + loadf(bias, co + 1, isbf);
  size_t eo = (size_t)gw * 64 + co;
  if (isbf) {
    unsigned int pk = (unsigned int)f2bf_bits(o0) | ((unsigned int)f2bf_bits(o1) << 16);
    *reinterpret_cast<unsigned int*>((unsigned short*)dout + eo) = pk;
  } else {
    float2 fo; fo.x = o0; fo.y = o1;
    *reinterpret_cast<float2*>((float*)dout + eo) = fo;
  }
}

extern "C" void kernel_launch(void* const* d_in, const int* in_sizes, int n_in,
                              void* d_out, int out_size, void* d_ws, size_t ws_size,
                              hipStream_t stream) {
  const void* x    = d_in[0];
  const void* ei   = d_in[1];
  const void* W1   = d_in[4];
  const void* b1   = d_in[5];
  const void* Wc0  = d_in[6];
  const void* bc0  = d_in[7];
  const void* Wc1  = d_in[8];
  const void* bc1  = d_in[9];
  const void* Wout = d_in[10];
  const void* bout = d_in[11];
  const void *bn1g = d_in[12], *bn1b = d_in[13], *bn1rm = d_in[14], *bn1rv = d_in[15];
  const void *bc0g = d_in[16], *bc0b = d_in[17], *bc0rm = d_in[18], *bc0rv = d_in[19];
  const void *bc1g = d_in[20], *bc1b = d_in[21], *bc1rm = d_in[22], *bc1rv = d_in[23];
  const void *bn2g = d_in[24], *bn2b = d_in[25], *bn2rm = d_in[26], *bn2rv = d_in[27];
  (void)in_sizes; (void)n_in; (void)out_size; (void)ws_size;

  char* w = (char*)d_ws;
  auto carve = [&](size_t bytes) {
    char* p = w;
    w += (bytes + 255) & ~(size_t)255;
    return p;
  };
  int*   flags  = (int*)  carve(256);
  float* dinv   = (float*)carve(sizeof(float) * NN);
  int*   cnt    = (int*)  carve(sizeof(int) * NN);
  int*   indptr = (int*)  carve(sizeof(int) * (NN + 1));
  int*   bsum   = (int*)  carve(sizeof(int) * 256);
  int*   erow   = (int*)  carve(sizeof(int) * NE);
  int*   ecol   = (int*)  carve(sizeof(int) * NE);
  int*   rank   = (int*)  carve(sizeof(int) * NE);
  int*   srcs   = (int*)  carve(sizeof(int) * NE);
  unsigned short* Wtb = (unsigned short*)carve(sizeof(short) * 90112);
  float* cvec   = (float*)carve(sizeof(float) * 448);
  unsigned short* xb  = (unsigned short*)carve(sizeof(short) * (size_t)NN * 128);
  unsigned short* hb  = (unsigned short*)carve(sizeof(short) * (size_t)NN * 128);
  unsigned short* rb0 = (unsigned short*)carve(sizeof(short) * (size_t)NN * 128);
  unsigned short* rb1 = (unsigned short*)carve(sizeof(short) * (size_t)NN * 128);
  unsigned short* rb2 = (unsigned short*)carve(sizeof(short) * (size_t)NN * 128);

  const int gN = (NN + 255) / 256;
  const int gE = (NE + 255) / 256;
  const int nb = (NN + 255) / 256;
  const int gG = (NN + 63) / 64;
  const int gA2 = (NN + 3) / 4;          // agg128: 4 waves/block, 1 node/wave
  const int gA1 = (NN + 7) / 8;          // agg64out: 8 half-waves/block

  k_sniff<<<gN, 256, 0, stream>>>(x, ei, flags, cnt);
  k_cvt_edges<<<gE, 256, 0, stream>>>(ei, erow, ecol, rank, cnt, flags);
  k_cvt_xb<<<(NN * 128 / 4 + 255) / 256, 256, 0, stream>>>(x, xb, flags);
  k_scan1<<<nb, 256, 0, stream>>>(cnt, indptr, bsum, dinv, NN);
  k_scan2<<<1, 256, 0, stream>>>(bsum, nb);
  k_scan3<<<(NN + 1 + 255) / 256, 256, 0, stream>>>(indptr, bsum, NN, nb);
  k_fill<<<gE, 256, 0, stream>>>(erow, ecol, rank, indptr, srcs);
  k_prep_wt_all<<<(90112 + 255) / 256, 256, 0, stream>>>(
      W1, Wc0, Wc1, Wout, bn1g, bc0g, bc1g, bn2g, bn1rv, bc0rv, bc1rv, bn2rv, Wtb, flags);
  k_prep_c_all<<<448, 64, 0, stream>>>(
      W1, Wc0, Wc1, Wout, bn1g, bc0g, bc1g, bn2g, bn1b, bc0b, bc1b, bn2b,
      bn1rm, bc0rm, bc1rm, bn2rm, bn1rv, bc0rv, bc1rv, bn2rv, cvec, flags);

  const size_t offO  = 0;
  const size_t offR0 = (size_t)NN * 64;
  const size_t offR1 = offR0 + (size_t)NN * 128;
  const size_t offR2 = offR1 + (size_t)NN * 128;
  unsigned short* d0 = (unsigned short*)d_out;   // bf16 view of regions

  // L1: bn1 + W1 (128->128), relu -> r0  (bf16 path reads x directly)
  k_gemm_mfma<128, 128><<<gG, 256, 0, stream>>>(
      xb, nullptr, nullptr, (const unsigned short*)x, nullptr, nullptr,
      Wtb + 0, cvec + 0, dinv, hb, flags);
  k_agg128<true><<<gA2, 256, 0, stream>>>(hb, indptr, srcs, dinv, b1, d_out, offR0, rb0, flags);

  // L2: bnc0 + Wc0 (128->128), relu -> r1
  k_gemm_mfma<128, 128><<<gG, 256, 0, stream>>>(
      rb0, nullptr, nullptr, d0 + offR0, nullptr, nullptr, Wtb + 16384, cvec + 128, dinv, hb, flags);
  k_agg128<true><<<gA2, 256, 0, stream>>>(hb, indptr, srcs, dinv, bc0, d_out, offR1, rb1, flags);

  // L3: bnc1 + Wc1 (256->128), relu -> r2
  k_gemm_mfma<128, 256><<<gG, 256, 0, stream>>>(
      rb0, rb1, nullptr, d0 + offR0, d0 + offR1, nullptr, Wtb + 32768, cvec + 256, dinv, hb, flags);
  k_agg128<true><<<gA2, 256, 0, stream>>>(hb, indptr, srcs, dinv, bc1, d_out, offR2, rb2, flags);

  // L4: bn2 + Wout (384->64), no relu -> out
  k_gemm_mfma<64, 384><<<gG, 256, 0, stream>>>(
      rb0, rb1, rb2, d0 + offR0, d0 + offR1, d0 + offR2, Wtb + 65536, cvec + 384, dinv, hb, flags);
  k_agg64out<<<gA1, 256, 0, stream>>>(hb, indptr, srcs, dinv, bout, d_out, flags);
}

// Round 11
// 333.545 us; speedup vs baseline: 1.0618x; 1.0618x over previous
//
#include <hip/hip_runtime.h>
#include <hip/hip_bf16.h>
#include <stdint.h>

#define NN 50000
#define NE 800000

typedef unsigned short ushort8 __attribute__((ext_vector_type(8)));
typedef __bf16 bf16x8 __attribute__((ext_vector_type(8)));
typedef float f32x4 __attribute__((ext_vector_type(4)));

// ---------- dtype helpers ----------
__device__ __forceinline__ float bf2f_bits(unsigned short u) {
  unsigned int x = ((unsigned int)u) << 16;
  float f;
  __builtin_memcpy(&f, &x, 4);
  return f;
}
__device__ __forceinline__ unsigned short f2bf_bits(float f) {
  unsigned int x;
  __builtin_memcpy(&x, &f, 4);
  unsigned int lsb = (x >> 16) & 1u;
  x += 0x7fffu + lsb;                       // round to nearest even
  return (unsigned short)(x >> 16);
}
__device__ __forceinline__ float lo16(unsigned int v) { return bf2f_bits((unsigned short)v); }
__device__ __forceinline__ float hi16(unsigned int v) { return bf2f_bits((unsigned short)(v >> 16)); }
__device__ __forceinline__ float loadf(const void* base, size_t idx, int isbf) {
  if (isbf) return bf2f_bits(((const unsigned short*)base)[idx]);
  return ((const float*)base)[idx];
}

// ---------- dtype sniff (block 0) + cnt8 zeroing (all blocks) ----------
__global__ void k_sniff(const void* x, const void* ei, int* flags, int* cnt8) {
  int i = blockIdx.x * 256 + threadIdx.x;
  if (i < 8 * NN) cnt8[i] = 0;
  if (blockIdx.x != 0) return;
  __shared__ int badbf;
  __shared__ int zodd;
  int tid = threadIdx.x;
  if (tid == 0) { badbf = 0; zodd = 0; }
  __syncthreads();
  unsigned short u = ((const unsigned short*)x)[tid];
  float v = bf2f_bits(u);
  float av = fabsf(v);
  int ok = (av == 0.0f) || (av > 1e-8f && av < 1e8f);
  if (!ok) atomicAdd(&badbf, 1);
  int e32 = ((const int*)ei)[tid];
  if ((tid & 1) && e32 == 0) atomicAdd(&zodd, 1);
  __syncthreads();
  if (tid == 0) {
    flags[0] = (badbf <= 12) ? 1 : 0;
    flags[1] = (zodd >= 100) ? 1 : 0;
  }
}

// convert edges + XCD-sharded degree count + per-edge (shard,rank) in one pass.
// True XCD id via HW_REG_XCC_ID [measured: learn_hip m09] -> each shard's
// counter lines are touched by ONE XCD's L2 only (no cross-XCD atomic
// ping-pong). Shard recorded in rank's high bits -> correctness is
// mapping-independent. (R6: few-counter scheme 282us; R9: blockIdx&7 guess
// was net-negative — both lessons folded in here.)
__global__ void k_cvt_edges(const void* ei, int* erow, int* ecol, int* rank,
                            int* cnt8, const int* flags) {
  int e = blockIdx.x * 256 + threadIdx.x;
  if (e >= NE) return;
  unsigned int xcc;
  asm volatile("s_getreg_b32 %0, hwreg(HW_REG_XCC_ID)" : "=s"(xcc));
  xcc &= 7;
  int r, c;
  if (flags[1]) {
    const long long* p = (const long long*)ei;
    r = (int)p[e];
    c = (int)p[NE + e];
  } else {
    const int* p = (const int*)ei;
    r = p[e];
    c = p[NE + e];
  }
  erow[e] = r;
  ecol[e] = c;
  int rl = atomicAdd(&cnt8[xcc * NN + c], 1);
  rank[e] = rl | (int)(xcc << 27);
}

// x (fp32) -> bf16 internal; no-op when device tensors already bf16
__global__ void k_cvt_xb(const void* x, unsigned short* xb, const int* flags) {
  if (flags[0]) return;
  int i4 = (blockIdx.x * 256 + threadIdx.x) * 4;
  if (i4 >= NN * 128) return;
  float4 v = *reinterpret_cast<const float4*>((const float*)x + i4);
  xb[i4 + 0] = f2bf_bits(v.x); xb[i4 + 1] = f2bf_bits(v.y);
  xb[i4 + 2] = f2bf_bits(v.z); xb[i4 + 3] = f2bf_bits(v.w);
}

// ---------- degree / CSR ----------
// Sums 8 shards -> total degree; writes per-shard EXCLUSIVE offsets back into
// cnt8 in place (thread owns node i); then block-local scan of totals + dinv.
__global__ void k_scan1(int* cnt8, int* indptr, int* bsum, float* dinv, int n) {
  __shared__ int sm[256];
  int tid = threadIdx.x;
  int i = blockIdx.x * 256 + tid;
  int v = 0;
  if (i < n) {
    int run = 0;
#pragma unroll
    for (int s = 0; s < 8; ++s) {
      int cs = cnt8[s * NN + i];
      cnt8[s * NN + i] = run;        // exclusive shard offset
      run += cs;
    }
    v = run;
    dinv[i] = rsqrtf((float)(v + 1));   // +1 self loop
  }
  sm[tid] = v;
  __syncthreads();
  for (int off = 1; off < 256; off <<= 1) {
    int t = (tid >= off) ? sm[tid - off] : 0;
    __syncthreads();
    sm[tid] += t;
    __syncthreads();
  }
  if (i < n) indptr[i] = sm[tid] - v;
  if (tid == 255) bsum[blockIdx.x] = sm[255];
}
__global__ void k_scan2(int* bsum, int nb) {
  __shared__ int sm[256];
  int tid = threadIdx.x;
  int v = (tid < nb) ? bsum[tid] : 0;
  sm[tid] = v;
  __syncthreads();
  for (int off = 1; off < 256; off <<= 1) {
    int t = (tid >= off) ? sm[tid - off] : 0;
    __syncthreads();
    sm[tid] += t;
    __syncthreads();
  }
  if (tid < nb) bsum[tid] = sm[tid] - v;
  if (tid == 0) bsum[nb] = sm[255];
}
__global__ void k_scan3(int* indptr, const int* bsum, int n, int nb) {
  int i = blockIdx.x * 256 + threadIdx.x;
  if (i < n) indptr[i] += bsum[i >> 8];
  else if (i == n) indptr[n] = bsum[nb];
}
// atomic-free fill: slot = indptr[c] + shard_offset[shard][c] + local rank
__global__ void k_fill(const int* erow, const int* ecol, const int* rank,
                       const int* indptr, const int* cnt8, int* srcs) {
  int e = blockIdx.x * 256 + threadIdx.x;
  if (e >= NE) return;
  int c = ecol[e];
  int rk = rank[e];
  int sh = (unsigned int)rk >> 27;
  srcs[indptr[c] + cnt8[sh * NN + c] + (rk & 0x07FFFFFF)] = erow[e];
}

// ---------- BN folding (all 4 layers fused) ----------
__global__ void k_prep_wt_all(
    const void* W1, const void* Wc0, const void* Wc1, const void* Wout,
    const void* g1, const void* g2, const void* g3, const void* g4,
    const void* rv1, const void* rv2, const void* rv3, const void* rv4,
    unsigned short* Wtb, const int* flags) {
  int idx = blockIdx.x * 256 + threadIdx.x;
  if (idx >= 90112) return;
  int isbf = flags[0];
  const void *W, *g, *rv;
  int K, NOUT, base;
  if (idx < 16384)      { W = W1;   g = g1; rv = rv1; K = 128; NOUT = 128; base = 0; }
  else if (idx < 32768) { W = Wc0;  g = g2; rv = rv2; K = 128; NOUT = 128; base = 16384; }
  else if (idx < 65536) { W = Wc1;  g = g3; rv = rv3; K = 256; NOUT = 128; base = 32768; }
  else                  { W = Wout; g = g4; rv = rv4; K = 384; NOUT = 64;  base = 65536; }
  int li = idx - base;
  int j = li / K, k = li % K;
  float s = loadf(g, k, isbf) * rsqrtf(loadf(rv, k, isbf) + 1e-5f);
  Wtb[idx] = f2bf_bits(s * loadf(W, (size_t)k * NOUT + j, isbf));
}
__global__ void k_prep_c_all(
    const void* W1, const void* Wc0, const void* Wc1, const void* Wout,
    const void* g1, const void* g2, const void* g3, const void* g4,
    const void* b1, const void* b2, const void* b3, const void* b4,
    const void* rm1, const void* rm2, const void* rm3, const void* rm4,
    const void* rv1, const void* rv2, const void* rv3, const void* rv4,
    float* cvec, const int* flags) {
  int jj = blockIdx.x;        // 0..447
  int lane = threadIdx.x;
  int isbf = flags[0];
  const void *W, *g, *bb, *rm, *rv;
  int K, NOUT, j;
  if (jj < 128)      { W = W1;   g = g1; bb = b1; rm = rm1; rv = rv1; K = 128; NOUT = 128; j = jj; }
  else if (jj < 256) { W = Wc0;  g = g2; bb = b2; rm = rm2; rv = rv2; K = 128; NOUT = 128; j = jj - 128; }
  else if (jj < 384) { W = Wc1;  g = g3; bb = b3; rm = rm3; rv = rv3; K = 256; NOUT = 128; j = jj - 256; }
  else               { W = Wout; g = g4; bb = b4; rm = rm4; rv = rv4; K = 384; NOUT = 64;  j = jj - 384; }
  float acc = 0.f;
  for (int k = lane; k < K; k += 64) {
    float s = loadf(g, k, isbf) * rsqrtf(loadf(rv, k, isbf) + 1e-5f);
    float t = loadf(bb, k, isbf) - loadf(rm, k, isbf) * s;
    acc += t * loadf(W, (size_t)k * NOUT + j, isbf);
  }
#pragma unroll
  for (int off = 32; off; off >>= 1) acc += __shfl_down(acc, off);
  if (lane == 0) cvec[jj] = acc;
}

// ---------- MFMA GEMM; A source selected at runtime (bf16: d_out/x direct) ----
template <int NOUT, int K>
__global__ __launch_bounds__(256) void k_gemm_mfma(
    const unsigned short* __restrict__ h0b, const unsigned short* __restrict__ h1b,
    const unsigned short* __restrict__ h2b,
    const unsigned short* __restrict__ h0d, const unsigned short* __restrict__ h1d,
    const unsigned short* __restrict__ h2d,
    const unsigned short* __restrict__ Wtb,
    const float* __restrict__ cvec, const float* __restrict__ dinv,
    unsigned short* __restrict__ hb, const int* __restrict__ flags) {
  constexpr int KS = K / 32;
  constexpr int NT = NOUT / 16;
  int isbf = flags[0];
  const unsigned short* h0 = (isbf && h0d) ? h0d : h0b;
  const unsigned short* h1 = (isbf && h1d) ? h1d : h1b;
  const unsigned short* h2 = (isbf && h2d) ? h2d : h2b;
  int tid = threadIdx.x;
  int wv = tid >> 6, lane = tid & 63;
  int row0 = blockIdx.x * 64 + wv * 16;
  int l15 = lane & 15;
  int kq = lane >> 4;
  int arow = row0 + l15;
  bool inb = arow < NN;

  bf16x8 afrag[KS];
#pragma unroll
  for (int ks = 0; ks < KS; ++ks) {
    int kg = ks * 32 + kq * 8;
    const unsigned short* src = (kg >> 7) == 0 ? h0 : ((kg >> 7) == 1 ? h1 : h2);
    ushort8 u = (ushort8)0;
    if (inb) u = *reinterpret_cast<const ushort8*>(src + (size_t)arow * 128 + (kg & 127));
    afrag[ks] = __builtin_bit_cast(bf16x8, u);
  }

  f32x4 acc[NT];
#pragma unroll
  for (int nt = 0; nt < NT; ++nt) acc[nt] = (f32x4)0.f;

#pragma unroll
  for (int nt = 0; nt < NT; ++nt) {
    const unsigned short* wrow = Wtb + (size_t)(nt * 16 + l15) * K + kq * 8;
#pragma unroll
    for (int ks = 0; ks < KS; ++ks) {
      ushort8 u = *reinterpret_cast<const ushort8*>(wrow + ks * 32);
      acc[nt] = __builtin_amdgcn_mfma_f32_16x16x32_bf16(
          afrag[ks], __builtin_bit_cast(bf16x8, u), acc[nt], 0, 0, 0);
    }
  }

  int orow0 = row0 + kq * 4;
  float dv[4];
  bool ob[4];
#pragma unroll
  for (int r = 0; r < 4; ++r) {
    int orow = orow0 + r;
    ob[r] = orow < NN;
    dv[r] = ob[r] ? dinv[orow] : 0.f;
  }
#pragma unroll
  for (int nt = 0; nt < NT; ++nt) {
    int col = nt * 16 + l15;
    float cv = cvec[col];
#pragma unroll
    for (int r = 0; r < 4; ++r) {
      if (ob[r])
        hb[(size_t)(orow0 + r) * NOUT + col] = f2bf_bits(dv[r] * (acc[nt][r] + cv));
    }
  }
}

// ---------- aggregation (128-wide): one WAVE per node (R8 layout, measured best) ----
template <bool RELU>
__global__ __launch_bounds__(256) void k_agg128(
    const unsigned short* __restrict__ hb, const int* __restrict__ indptr,
    const int* __restrict__ srcs, const float* __restrict__ dinv,
    const void* __restrict__ bias, void* __restrict__ dout, size_t region_off,
    unsigned short* __restrict__ rb, const int* __restrict__ flags) {
  int gw = __builtin_amdgcn_readfirstlane(blockIdx.x * 4 + (threadIdx.x >> 6));
  int lane = threadIdx.x & 63;
  if (gw >= NN) return;
  int isbf = flags[0];
  int e0 = indptr[gw], e1 = indptr[gw + 1];
  size_t co = (size_t)lane * 2;               // 2 bf16 per lane = 4B
  unsigned int sv = *reinterpret_cast<const unsigned int*>(hb + (size_t)gw * 128 + co);
  float a0 = lo16(sv), a1 = hi16(sv);
  float b0 = 0.f, b1 = 0.f, c0 = 0.f, c1 = 0.f, d0 = 0.f, d1 = 0.f;
  int e = e0;
  for (; e + 7 < e1; e += 8) {                // 8 rows in flight per wave
    int s0 = srcs[e], s1 = srcs[e + 1], s2 = srcs[e + 2], s3 = srcs[e + 3];
    int s4 = srcs[e + 4], s5 = srcs[e + 5], s6 = srcs[e + 6], s7 = srcs[e + 7];
    unsigned int v0 = *reinterpret_cast<const unsigned int*>(hb + (size_t)s0 * 128 + co);
    unsigned int v1 = *reinterpret_cast<const unsigned int*>(hb + (size_t)s1 * 128 + co);
    unsigned int v2 = *reinterpret_cast<const unsigned int*>(hb + (size_t)s2 * 128 + co);
    unsigned int v3 = *reinterpret_cast<const unsigned int*>(hb + (size_t)s3 * 128 + co);
    unsigned int v4 = *reinterpret_cast<const unsigned int*>(hb + (size_t)s4 * 128 + co);
    unsigned int v5 = *reinterpret_cast<const unsigned int*>(hb + (size_t)s5 * 128 + co);
    unsigned int v6 = *reinterpret_cast<const unsigned int*>(hb + (size_t)s6 * 128 + co);
    unsigned int v7 = *reinterpret_cast<const unsigned int*>(hb + (size_t)s7 * 128 + co);
    a0 += lo16(v0); a1 += hi16(v0); b0 += lo16(v1); b1 += hi16(v1);
    c0 += lo16(v2); c1 += hi16(v2); d0 += lo16(v3); d1 += hi16(v3);
    a0 += lo16(v4); a1 += hi16(v4); b0 += lo16(v5); b1 += hi16(v5);
    c0 += lo16(v6); c1 += hi16(v6); d0 += lo16(v7); d1 += hi16(v7);
  }
  for (; e < e1; ++e) {
    int s0 = srcs[e];
    unsigned int v0 = *reinterpret_cast<const unsigned int*>(hb + (size_t)s0 * 128 + co);
    a0 += lo16(v0); a1 += hi16(v0);
  }
  float dv = dinv[gw];
  float o0 = dv * ((a0 + b0) + (c0 + d0)) + loadf(bias, co + 0, isbf);
  float o1 = dv * ((a1 + b1) + (c1 + d1)) + loadf(bias, co + 1, isbf);
  if (RELU) { o0 = fmaxf(o0, 0.f); o1 = fmaxf(o1, 0.f); }
  size_t eo = region_off + (size_t)gw * 128 + co;
  if (isbf) {
    // d_out region doubles as the residual buffer (read by next GEMM)
    unsigned int pk = (unsigned int)f2bf_bits(o0) | ((unsigned int)f2bf_bits(o1) << 16);
    *reinterpret_cast<unsigned int*>((unsigned short*)dout + eo) = pk;
  } else {
    float2 fo; fo.x = o0; fo.y = o1;
    *reinterpret_cast<float2*>((float*)dout + eo) = fo;
    unsigned int pk = (unsigned int)f2bf_bits(o0) | ((unsigned int)f2bf_bits(o1) << 16);
    *reinterpret_cast<unsigned int*>(rb + (size_t)gw * 128 + co) = pk;
  }
}

// ---------- aggregation (64-wide final layer): 32 lanes/node ----------
__global__ __launch_bounds__(256) void k_agg64out(
    const unsigned short* __restrict__ hb, const int* __restrict__ indptr,
    const int* __restrict__ srcs, const float* __restrict__ dinv,
    const void* __restrict__ bias, void* __restrict__ dout,
    const int* __restrict__ flags) {
  int gw = blockIdx.x * 8 + (threadIdx.x >> 5);
  int lane = threadIdx.x & 31;
  if (gw >= NN) return;
  int isbf = flags[0];
  int e0 = indptr[gw], e1 = indptr[gw + 1];
  int e = e0;
  size_t co = (size_t)lane * 2;
  unsigned int sv = *reinterpret_cast<const unsigned int*>(hb + (size_t)gw * 64 + co);
  float a0 = lo16(sv), a1 = hi16(sv);
  float b0 = 0.f, b1 = 0.f, c0 = 0.f, c1 = 0.f, d0 = 0.f, d1 = 0.f;
  for (; e + 3 < e1; e += 4) {
    int sa = srcs[e], sb = srcs[e + 1], sc = srcs[e + 2], sd = srcs[e + 3];
    unsigned int va = *reinterpret_cast<const unsigned int*>(hb + (size_t)sa * 64 + co);
    unsigned int vb = *reinterpret_cast<const unsigned int*>(hb + (size_t)sb * 64 + co);
    unsigned int vc = *reinterpret_cast<const unsigned int*>(hb + (size_t)sc * 64 + co);
    unsigned int vd = *reinterpret_cast<const unsigned int*>(hb + (size_t)sd * 64 + co);
    a0 += lo16(va); a1 += hi16(va); b0 += lo16(vb); b1 += hi16(vb);
    c0 += lo16(vc); c1 += hi16(vc); d0 += lo16(vd); d1 += hi16(vd);
  }
  for (; e < e1; ++e) {
    int sa = srcs[e];
    unsigned int va = *reinterpret_cast<const unsigned int*>(hb + (size_t)sa * 64 + co);
    a0 += lo16(va); a1 += hi16(va);
  }
  float dv = dinv[gw];
  float o0 = dv * ((a0 + b0) + (c0 + d0)) + loadf(bias, co + 0, isbf);
  float o1 = dv * ((a1 + b1) + (c1 + d1)) + loadf(bias, co + 1, isbf);
  size_t eo = (size_t)gw * 64 + co;
  if (isbf) {
    unsigned int pk = (unsigned int)f2bf_bits(o0) | ((unsigned int)f2bf_bits(o1) << 16);
    *reinterpret_cast<unsigned int*>((unsigned short*)dout + eo) = pk;
  } else {
    float2 fo; fo.x = o0; fo.y = o1;
    *reinterpret_cast<float2*>((float*)dout + eo) = fo;
  }
}

extern "C" void kernel_launch(void* const* d_in, const int* in_sizes, int n_in,
                              void* d_out, int out_size, void* d_ws, size_t ws_size,
                              hipStream_t stream) {
  const void* x    = d_in[0];
  const void* ei   = d_in[1];
  const void* W1   = d_in[4];
  const void* b1   = d_in[5];
  const void* Wc0  = d_in[6];
  const void* bc0  = d_in[7];
  const void* Wc1  = d_in[8];
  const void* bc1  = d_in[9];
  const void* Wout = d_in[10];
  const void* bout = d_in[11];
  const void *bn1g = d_in[12], *bn1b = d_in[13], *bn1rm = d_in[14], *bn1rv = d_in[15];
  const void *bc0g = d_in[16], *bc0b = d_in[17], *bc0rm = d_in[18], *bc0rv = d_in[19];
  const void *bc1g = d_in[20], *bc1b = d_in[21], *bc1rm = d_in[22], *bc1rv = d_in[23];
  const void *bn2g = d_in[24], *bn2b = d_in[25], *bn2rm = d_in[26], *bn2rv = d_in[27];
  (void)in_sizes; (void)n_in; (void)out_size; (void)ws_size;

  char* w = (char*)d_ws;
  auto carve = [&](size_t bytes) {
    char* p = w;
    w += (bytes + 255) & ~(size_t)255;
    return p;
  };
  int*   flags  = (int*)  carve(256);
  float* dinv   = (float*)carve(sizeof(float) * NN);
  int*   cnt8   = (int*)  carve(sizeof(int) * 8 * NN);
  int*   indptr = (int*)  carve(sizeof(int) * (NN + 1));
  int*   bsum   = (int*)  carve(sizeof(int) * 256);
  int*   erow   = (int*)  carve(sizeof(int) * NE);
  int*   ecol   = (int*)  carve(sizeof(int) * NE);
  int*   rank   = (int*)  carve(sizeof(int) * NE);
  int*   srcs   = (int*)  carve(sizeof(int) * NE);
  unsigned short* Wtb = (unsigned short*)carve(sizeof(short) * 90112);
  float* cvec   = (float*)carve(sizeof(float) * 448);
  unsigned short* xb  = (unsigned short*)carve(sizeof(short) * (size_t)NN * 128);
  unsigned short* hb  = (unsigned short*)carve(sizeof(short) * (size_t)NN * 128);
  unsigned short* rb0 = (unsigned short*)carve(sizeof(short) * (size_t)NN * 128);
  unsigned short* rb1 = (unsigned short*)carve(sizeof(short) * (size_t)NN * 128);
  unsigned short* rb2 = (unsigned short*)carve(sizeof(short) * (size_t)NN * 128);

  const int gN8 = (8 * NN + 255) / 256;
  const int gE = (NE + 255) / 256;
  const int nb = (NN + 255) / 256;
  const int gG = (NN + 63) / 64;
  const int gA2 = (NN + 3) / 4;          // agg128: 4 waves/block, 1 node/wave
  const int gA1 = (NN + 7) / 8;          // agg64out: 8 half-waves/block

  k_sniff<<<gN8, 256, 0, stream>>>(x, ei, flags, cnt8);
  k_cvt_edges<<<gE, 256, 0, stream>>>(ei, erow, ecol, rank, cnt8, flags);
  k_cvt_xb<<<(NN * 128 / 4 + 255) / 256, 256, 0, stream>>>(x, xb, flags);
  k_scan1<<<nb, 256, 0, stream>>>(cnt8, indptr, bsum, dinv, NN);
  k_scan2<<<1, 256, 0, stream>>>(bsum, nb);
  k_scan3<<<(NN + 1 + 255) / 256, 256, 0, stream>>>(indptr, bsum, NN, nb);
  k_fill<<<gE, 256, 0, stream>>>(erow, ecol, rank, indptr, cnt8, srcs);
  k_prep_wt_all<<<(90112 + 255) / 256, 256, 0, stream>>>(
      W1, Wc0, Wc1, Wout, bn1g, bc0g, bc1g, bn2g, bn1rv, bc0rv, bc1rv, bn2rv, Wtb, flags);
  k_prep_c_all<<<448, 64, 0, stream>>>(
      W1, Wc0, Wc1, Wout, bn1g, bc0g, bc1g, bn2g, bn1b, bc0b, bc1b, bn2b,
      bn1rm, bc0rm, bc1rm, bn2rm, bn1rv, bc0rv, bc1rv, bn2rv, cvec, flags);

  const size_t offO  = 0;
  const size_t offR0 = (size_t)NN * 64;
  const size_t offR1 = offR0 + (size_t)NN * 128;
  const size_t offR2 = offR1 + (size_t)NN * 128;
  unsigned short* d0 = (unsigned short*)d_out;   // bf16 view of regions

  // L1: bn1 + W1 (128->128), relu -> r0  (bf16 path reads x directly)
  k_gemm_mfma<128, 128><<<gG, 256, 0, stream>>>(
      xb, nullptr, nullptr, (const unsigned short*)x, nullptr, nullptr,
      Wtb + 0, cvec + 0, dinv, hb, flags);
  k_agg128<true><<<gA2, 256, 0, stream>>>(hb, indptr, srcs, dinv, b1, d_out, offR0, rb0, flags);

  // L2: bnc0 + Wc0 (128->128), relu -> r1
  k_gemm_mfma<128, 128><<<gG, 256, 0, stream>>>(
      rb0, nullptr, nullptr, d0 + offR0, nullptr, nullptr, Wtb + 16384, cvec + 128, dinv, hb, flags);
  k_agg128<true><<<gA2, 256, 0, stream>>>(hb, indptr, srcs, dinv, bc0, d_out, offR1, rb1, flags);

  // L3: bnc1 + Wc1 (256->128), relu -> r2
  k_gemm_mfma<128, 256><<<gG, 256, 0, stream>>>(
      rb0, rb1, nullptr, d0 + offR0, d0 + offR1, nullptr, Wtb + 32768, cvec + 256, dinv, hb, flags);
  k_agg128<true><<<gA2, 256, 0, stream>>>(hb, indptr, srcs, dinv, bc1, d_out, offR2, rb2, flags);

  // L4: bn2 + Wout (384->64), no relu -> out
  k_gemm_mfma<64, 384><<<gG, 256, 0, stream>>>(
      rb0, rb1, rb2, d0 + offR0, d0 + offR1, d0 + offR2, Wtb + 65536, cvec + 384, dinv, hb, flags);
  k_agg64out<<<gA1, 256, 0, stream>>>(hb, indptr, srcs, dinv, bout, d_out, flags);
}

// Round 12
// 317.272 us; speedup vs baseline: 1.1163x; 1.0513x over previous
//
#include <hip/hip_runtime.h>
#include <hip/hip_bf16.h>
#include <stdint.h>

#define NN 50000
#define NE 800000
#define GE 3125                    // edge blocks (NE/256)
#define GX 6250                    // cvt_xb blocks (NN*128/4/256)
#define GW 352                     // prep_wt blocks (90112/256)
#define GC 112                     // prep_c blocks (448 cols / 4 per block)
#define NB 196                     // scan blocks ((NN+255)/256)

typedef unsigned short ushort8 __attribute__((ext_vector_type(8)));
typedef __bf16 bf16x8 __attribute__((ext_vector_type(8)));
typedef float f32x4 __attribute__((ext_vector_type(4)));

// ---------- dtype helpers ----------
__device__ __forceinline__ float bf2f_bits(unsigned short u) {
  unsigned int x = ((unsigned int)u) << 16;
  float f;
  __builtin_memcpy(&f, &x, 4);
  return f;
}
__device__ __forceinline__ unsigned short f2bf_bits(float f) {
  unsigned int x;
  __builtin_memcpy(&x, &f, 4);
  unsigned int lsb = (x >> 16) & 1u;
  x += 0x7fffu + lsb;                       // round to nearest even
  return (unsigned short)(x >> 16);
}
__device__ __forceinline__ float lo16(unsigned int v) { return bf2f_bits((unsigned short)v); }
__device__ __forceinline__ float hi16(unsigned int v) { return bf2f_bits((unsigned short)(v >> 16)); }
__device__ __forceinline__ float loadf(const void* base, size_t idx, int isbf) {
  if (isbf) return bf2f_bits(((const unsigned short*)base)[idx]);
  return ((const float*)base)[idx];
}

// ---------- launch 1: dtype sniff (block 0) + cnt8 zeroing ----------
__global__ void k_sniff(const void* x, const void* ei, int* flags, int* cnt8) {
  int i = blockIdx.x * 256 + threadIdx.x;
  if (i < 8 * NN) cnt8[i] = 0;
  if (blockIdx.x != 0) return;
  __shared__ int badbf;
  __shared__ int zodd;
  int tid = threadIdx.x;
  if (tid == 0) { badbf = 0; zodd = 0; }
  __syncthreads();
  unsigned short u = ((const unsigned short*)x)[tid];
  float v = bf2f_bits(u);
  float av = fabsf(v);
  int ok = (av == 0.0f) || (av > 1e-8f && av < 1e8f);
  if (!ok) atomicAdd(&badbf, 1);
  int e32 = ((const int*)ei)[tid];
  if ((tid & 1) && e32 == 0) atomicAdd(&zodd, 1);
  __syncthreads();
  if (tid == 0) {
    flags[0] = (badbf <= 12) ? 1 : 0;
    flags[1] = (zodd >= 100) ? 1 : 0;
  }
}

// ---------- launch 2: cvt_edges || cvt_xb || prep_wt || prep_c (all flag-dep only) ----------
// XCD-sharded degree count (HW_REG_XCC_ID, learn_hip m09): shard counter lines
// stay in one XCD's L2; shard id in rank high bits -> mapping-independent.
__global__ __launch_bounds__(256) void k_fuse_prep(
    const void* ei, const void* x, unsigned short* xb, int* rank, int* cnt8,
    const void* W1, const void* Wc0, const void* Wc1, const void* Wout,
    const void* g1, const void* g2, const void* g3, const void* g4,
    const void* b1, const void* b2, const void* b3, const void* b4,
    const void* rm1, const void* rm2, const void* rm3, const void* rm4,
    const void* rv1, const void* rv2, const void* rv3, const void* rv4,
    unsigned short* Wtb, float* cvec, const int* flags) {
  int bid = blockIdx.x;
  int tid = threadIdx.x;
  if (bid < GE) {                       // --- edge convert + sharded count ---
    int e = bid * 256 + tid;
    if (e >= NE) return;
    unsigned int xcc;
    asm volatile("s_getreg_b32 %0, hwreg(HW_REG_XCC_ID)" : "=s"(xcc));
    xcc &= 7;
    int c;
    if (flags[1]) c = (int)((const long long*)ei)[NE + e];
    else          c = ((const int*)ei)[NE + e];
    int rl = atomicAdd(&cnt8[xcc * NN + c], 1);
    rank[e] = rl | (int)(xcc << 27);
    return;
  }
  bid -= GE;
  if (bid < GX) {                       // --- x -> bf16 (fp32 path only) ---
    if (flags[0]) return;
    int i4 = (bid * 256 + tid) * 4;
    if (i4 >= NN * 128) return;
    float4 v = *reinterpret_cast<const float4*>((const float*)x + i4);
    xb[i4 + 0] = f2bf_bits(v.x); xb[i4 + 1] = f2bf_bits(v.y);
    xb[i4 + 2] = f2bf_bits(v.z); xb[i4 + 3] = f2bf_bits(v.w);
    return;
  }
  bid -= GX;
  int isbf = flags[0];
  if (bid < GW) {                       // --- W' transpose bf16 ---
    int idx = bid * 256 + tid;
    if (idx >= 90112) return;
    const void *W, *g, *rv;
    int K, NOUT, base;
    if (idx < 16384)      { W = W1;   g = g1; rv = rv1; K = 128; NOUT = 128; base = 0; }
    else if (idx < 32768) { W = Wc0;  g = g2; rv = rv2; K = 128; NOUT = 128; base = 16384; }
    else if (idx < 65536) { W = Wc1;  g = g3; rv = rv3; K = 256; NOUT = 128; base = 32768; }
    else                  { W = Wout; g = g4; rv = rv4; K = 384; NOUT = 64;  base = 65536; }
    int li = idx - base;
    int j = li / K, k = li % K;
    float s = loadf(g, k, isbf) * rsqrtf(loadf(rv, k, isbf) + 1e-5f);
    Wtb[idx] = f2bf_bits(s * loadf(W, (size_t)k * NOUT + j, isbf));
    return;
  }
  bid -= GW;
  {                                     // --- cvec: 4 cols/block, 1 per wave ---
    int jj = bid * 4 + (tid >> 6);
    int lane = tid & 63;
    if (jj >= 448) return;
    const void *W, *g, *bb, *rm, *rv;
    int K, NOUT, j;
    if (jj < 128)      { W = W1;   g = g1; bb = b1; rm = rm1; rv = rv1; K = 128; NOUT = 128; j = jj; }
    else if (jj < 256) { W = Wc0;  g = g2; bb = b2; rm = rm2; rv = rv2; K = 128; NOUT = 128; j = jj - 128; }
    else if (jj < 384) { W = Wc1;  g = g3; bb = b3; rm = rm3; rv = rv3; K = 256; NOUT = 128; j = jj - 256; }
    else               { W = Wout; g = g4; bb = b4; rm = rm4; rv = rv4; K = 384; NOUT = 64;  j = jj - 384; }
    float acc = 0.f;
    for (int k = lane; k < K; k += 64) {
      float s = loadf(g, k, isbf) * rsqrtf(loadf(rv, k, isbf) + 1e-5f);
      float t = loadf(bb, k, isbf) - loadf(rm, k, isbf) * s;
      acc += t * loadf(W, (size_t)k * NOUT + j, isbf);
    }
#pragma unroll
    for (int off = 32; off; off >>= 1) acc += __shfl_down(acc, off);
    if (lane == 0) cvec[jj] = acc;
  }
}

// ---------- launch 3: scan1 (shard offsets in place + block totals + dinv) ----------
__global__ void k_scan1(int* cnt8, int* indptr, int* bsum, float* dinv, int n) {
  __shared__ int sm[256];
  int tid = threadIdx.x;
  int i = blockIdx.x * 256 + tid;
  int v = 0;
  if (i < n) {
    int run = 0;
#pragma unroll
    for (int s = 0; s < 8; ++s) {
      int cs = cnt8[s * NN + i];
      cnt8[s * NN + i] = run;        // exclusive shard offset
      run += cs;
    }
    v = run;
    dinv[i] = rsqrtf((float)(v + 1));   // +1 self loop
  }
  sm[tid] = v;
  __syncthreads();
  for (int off = 1; off < 256; off <<= 1) {
    int t = (tid >= off) ? sm[tid - off] : 0;
    __syncthreads();
    sm[tid] += t;
    __syncthreads();
  }
  if (i < n) indptr[i] = sm[tid] - v;
  if (tid == 255) bsum[blockIdx.x] = sm[255];
}

// ---------- launch 4: scan2+scan3 merged (each block reduces its own prefix) ----------
__global__ void k_scan23(int* indptr, const int* bsum, int n, int nb) {
  __shared__ int sm[256];
  int b = blockIdx.x;
  int tid = threadIdx.x;
  sm[tid] = (tid < nb && tid < b) ? bsum[tid] : 0;
  __syncthreads();
  for (int off = 128; off; off >>= 1) {
    if (tid < off) sm[tid] += sm[tid + off];
    __syncthreads();
  }
  int S = sm[0];
  int i = b * 256 + tid;
  if (i < n) indptr[i] += S;
  else if (i == n) indptr[n] = NE;       // grand total is known
}

// ---------- GEMM body (shared by fused L1 and standalone L2-L4) ----------
template <int NOUT, int K>
__device__ __forceinline__ void gemm_body(
    int bid,
    const unsigned short* __restrict__ h0, const unsigned short* __restrict__ h1,
    const unsigned short* __restrict__ h2,
    const unsigned short* __restrict__ Wtb,
    const float* __restrict__ cvec, const float* __restrict__ dinv,
    unsigned short* __restrict__ hb) {
  constexpr int KS = K / 32;
  constexpr int NT = NOUT / 16;
  int tid = threadIdx.x;
  int wv = tid >> 6, lane = tid & 63;
  int row0 = bid * 64 + wv * 16;
  int l15 = lane & 15;
  int kq = lane >> 4;
  int arow = row0 + l15;
  bool inb = arow < NN;

  bf16x8 afrag[KS];
#pragma unroll
  for (int ks = 0; ks < KS; ++ks) {
    int kg = ks * 32 + kq * 8;
    const unsigned short* src = (kg >> 7) == 0 ? h0 : ((kg >> 7) == 1 ? h1 : h2);
    ushort8 u = (ushort8)0;
    if (inb) u = *reinterpret_cast<const ushort8*>(src + (size_t)arow * 128 + (kg & 127));
    afrag[ks] = __builtin_bit_cast(bf16x8, u);
  }

  f32x4 acc[NT];
#pragma unroll
  for (int nt = 0; nt < NT; ++nt) acc[nt] = (f32x4)0.f;

#pragma unroll
  for (int nt = 0; nt < NT; ++nt) {
    const unsigned short* wrow = Wtb + (size_t)(nt * 16 + l15) * K + kq * 8;
#pragma unroll
    for (int ks = 0; ks < KS; ++ks) {
      ushort8 u = *reinterpret_cast<const ushort8*>(wrow + ks * 32);
      acc[nt] = __builtin_amdgcn_mfma_f32_16x16x32_bf16(
          afrag[ks], __builtin_bit_cast(bf16x8, u), acc[nt], 0, 0, 0);
    }
  }

  int orow0 = row0 + kq * 4;
  float dv[4];
  bool ob[4];
#pragma unroll
  for (int r = 0; r < 4; ++r) {
    int orow = orow0 + r;
    ob[r] = orow < NN;
    dv[r] = ob[r] ? dinv[orow] : 0.f;
  }
#pragma unroll
  for (int nt = 0; nt < NT; ++nt) {
    int col = nt * 16 + l15;
    float cv = cvec[col];
#pragma unroll
    for (int r = 0; r < 4; ++r) {
      if (ob[r])
        hb[(size_t)(orow0 + r) * NOUT + col] = f2bf_bits(dv[r] * (acc[nt][r] + cv));
    }
  }
}

// ---------- launch 5: fill || GEMM-L1 (independent; fill hides GEMM) ----------
__global__ __launch_bounds__(256) void k_fill_gemm1(
    const void* ei, const int* __restrict__ rank, const int* __restrict__ indptr,
    const int* __restrict__ cnt8, int* __restrict__ srcs,
    const unsigned short* __restrict__ h0b, const unsigned short* __restrict__ h0d,
    const unsigned short* __restrict__ Wtb, const float* __restrict__ cvec,
    const float* __restrict__ dinv, unsigned short* __restrict__ hb,
    const int* __restrict__ flags) {
  int bid = blockIdx.x;
  if (bid < GE) {                       // --- atomic-free scatter fill ---
    int e = bid * 256 + threadIdx.x;
    if (e >= NE) return;
    int r, c;
    if (flags[1]) {
      const long long* p = (const long long*)ei;
      r = (int)p[e];
      c = (int)p[NE + e];
    } else {
      const int* p = (const int*)ei;
      r = p[e];
      c = p[NE + e];
    }
    int rk = rank[e];
    int sh = (unsigned int)rk >> 27;
    srcs[indptr[c] + cnt8[sh * NN + c] + (rk & 0x07FFFFFF)] = r;
    return;
  }
  const unsigned short* h0 = (flags[0] && h0d) ? h0d : h0b;
  gemm_body<128, 128>(bid - GE, h0, nullptr, nullptr, Wtb, cvec, dinv, hb);
}

// ---------- standalone GEMM (L2-L4) ----------
template <int NOUT, int K>
__global__ __launch_bounds__(256) void k_gemm_mfma(
    const unsigned short* __restrict__ h0b, const unsigned short* __restrict__ h1b,
    const unsigned short* __restrict__ h2b,
    const unsigned short* __restrict__ h0d, const unsigned short* __restrict__ h1d,
    const unsigned short* __restrict__ h2d,
    const unsigned short* __restrict__ Wtb,
    const float* __restrict__ cvec, const float* __restrict__ dinv,
    unsigned short* __restrict__ hb, const int* __restrict__ flags) {
  int isbf = flags[0];
  const unsigned short* h0 = (isbf && h0d) ? h0d : h0b;
  const unsigned short* h1 = (isbf && h1d) ? h1d : h1b;
  const unsigned short* h2 = (isbf && h2d) ? h2d : h2b;
  gemm_body<NOUT, K>(blockIdx.x, h0, h1, h2, Wtb, cvec, dinv, hb);
}

// ---------- aggregation (128-wide): one WAVE per node (R8 layout, measured best) ----
template <bool RELU>
__global__ __launch_bounds__(256) void k_agg128(
    const unsigned short* __restrict__ hb, const int* __restrict__ indptr,
    const int* __restrict__ srcs, const float* __restrict__ dinv,
    const void* __restrict__ bias, void* __restrict__ dout, size_t region_off,
    unsigned short* __restrict__ rb, const int* __restrict__ flags) {
  int gw = __builtin_amdgcn_readfirstlane(blockIdx.x * 4 + (threadIdx.x >> 6));
  int lane = threadIdx.x & 63;
  if (gw >= NN) return;
  int isbf = flags[0];
  int e0 = indptr[gw], e1 = indptr[gw + 1];
  size_t co = (size_t)lane * 2;               // 2 bf16 per lane = 4B
  unsigned int sv = *reinterpret_cast<const unsigned int*>(hb + (size_t)gw * 128 + co);
  float a0 = lo16(sv), a1 = hi16(sv);
  float b0 = 0.f, b1 = 0.f, c0 = 0.f, c1 = 0.f, d0 = 0.f, d1 = 0.f;
  int e = e0;
  for (; e + 7 < e1; e += 8) {                // 8 rows in flight per wave
    int s0 = srcs[e], s1 = srcs[e + 1], s2 = srcs[e + 2], s3 = srcs[e + 3];
    int s4 = srcs[e + 4], s5 = srcs[e + 5], s6 = srcs[e + 6], s7 = srcs[e + 7];
    unsigned int v0 = *reinterpret_cast<const unsigned int*>(hb + (size_t)s0 * 128 + co);
    unsigned int v1 = *reinterpret_cast<const unsigned int*>(hb + (size_t)s1 * 128 + co);
    unsigned int v2 = *reinterpret_cast<const unsigned int*>(hb + (size_t)s2 * 128 + co);
    unsigned int v3 = *reinterpret_cast<const unsigned int*>(hb + (size_t)s3 * 128 + co);
    unsigned int v4 = *reinterpret_cast<const unsigned int*>(hb + (size_t)s4 * 128 + co);
    unsigned int v5 = *reinterpret_cast<const unsigned int*>(hb + (size_t)s5 * 128 + co);
    unsigned int v6 = *reinterpret_cast<const unsigned int*>(hb + (size_t)s6 * 128 + co);
    unsigned int v7 = *reinterpret_cast<const unsigned int*>(hb + (size_t)s7 * 128 + co);
    a0 += lo16(v0); a1 += hi16(v0); b0 += lo16(v1); b1 += hi16(v1);
    c0 += lo16(v2); c1 += hi16(v2); d0 += lo16(v3); d1 += hi16(v3);
    a0 += lo16(v4); a1 += hi16(v4); b0 += lo16(v5); b1 += hi16(v5);
    c0 += lo16(v6); c1 += hi16(v6); d0 += lo16(v7); d1 += hi16(v7);
  }
  for (; e < e1; ++e) {
    int s0 = srcs[e];
    unsigned int v0 = *reinterpret_cast<const unsigned int*>(hb + (size_t)s0 * 128 + co);
    a0 += lo16(v0); a1 += hi16(v0);
  }
  float dv = dinv[gw];
  float o0 = dv * ((a0 + b0) + (c0 + d0)) + loadf(bias, co + 0, isbf);
  float o1 = dv * ((a1 + b1) + (c1 + d1)) + loadf(bias, co + 1, isbf);
  if (RELU) { o0 = fmaxf(o0, 0.f); o1 = fmaxf(o1, 0.f); }
  size_t eo = region_off + (size_t)gw * 128 + co;
  if (isbf) {
    // d_out region doubles as the residual buffer (read by next GEMM)
    unsigned int pk = (unsigned int)f2bf_bits(o0) | ((unsigned int)f2bf_bits(o1) << 16);
    *reinterpret_cast<unsigned int*>((unsigned short*)dout + eo) = pk;
  } else {
    float2 fo; fo.x = o0; fo.y = o1;
    *reinterpret_cast<float2*>((float*)dout + eo) = fo;
    unsigned int pk = (unsigned int)f2bf_bits(o0) | ((unsigned int)f2bf_bits(o1) << 16);
    *reinterpret_cast<unsigned int*>(rb + (size_t)gw * 128 + co) = pk;
  }
}

// ---------- aggregation (64-wide final layer): 32 lanes/node ----------
__global__ __launch_bounds__(256) void k_agg64out(
    const unsigned short* __restrict__ hb, const int* __restrict__ indptr,
    const int* __restrict__ srcs, const float* __restrict__ dinv,
    const void* __restrict__ bias, void* __restrict__ dout,
    const int* __restrict__ flags) {
  int gw = blockIdx.x * 8 + (threadIdx.x >> 5);
  int lane = threadIdx.x & 31;
  if (gw >= NN) return;
  int isbf = flags[0];
  int e0 = indptr[gw], e1 = indptr[gw + 1];
  int e = e0;
  size_t co = (size_t)lane * 2;
  unsigned int sv = *reinterpret_cast<const unsigned int*>(hb + (size_t)gw * 64 + co);
  float a0 = lo16(sv), a1 = hi16(sv);
  float b0 = 0.f, b1 = 0.f, c0 = 0.f, c1 = 0.f, d0 = 0.f, d1 = 0.f;
  for (; e + 3 < e1; e += 4) {
    int sa = srcs[e], sb = srcs[e + 1], sc = srcs[e + 2], sd = srcs[e + 3];
    unsigned int va = *reinterpret_cast<const unsigned int*>(hb + (size_t)sa * 64 + co);
    unsigned int vb = *reinterpret_cast<const unsigned int*>(hb + (size_t)sb * 64 + co);
    unsigned int vc = *reinterpret_cast<const unsigned int*>(hb + (size_t)sc * 64 + co);
    unsigned int vd = *reinterpret_cast<const unsigned int*>(hb + (size_t)sd * 64 + co);
    a0 += lo16(va); a1 += hi16(va); b0 += lo16(vb); b1 += hi16(vb);
    c0 += lo16(vc); c1 += hi16(vc); d0 += lo16(vd); d1 += hi16(vd);
  }
  for (; e < e1; ++e) {
    int sa = srcs[e];
    unsigned int va = *reinterpret_cast<const unsigned int*>(hb + (size_t)sa * 64 + co);
    a0 += lo16(va); a1 += hi16(va);
  }
  float dv = dinv[gw];
  float o0 = dv * ((a0 + b0) + (c0 + d0)) + loadf(bias, co + 0, isbf);
  float o1 = dv * ((a1 + b1) + (c1 + d1)) + loadf(bias, co + 1, isbf);
  size_t eo = (size_t)gw * 64 + co;
  if (isbf) {
    unsigned int pk = (unsigned int)f2bf_bits(o0) | ((unsigned int)f2bf_bits(o1) << 16);
    *reinterpret_cast<unsigned int*>((unsigned short*)dout + eo) = pk;
  } else {
    float2 fo; fo.x = o0; fo.y = o1;
    *reinterpret_cast<float2*>((float*)dout + eo) = fo;
  }
}

extern "C" void kernel_launch(void* const* d_in, const int* in_sizes, int n_in,
                              void* d_out, int out_size, void* d_ws, size_t ws_size,
                              hipStream_t stream) {
  const void* x    = d_in[0];
  const void* ei   = d_in[1];
  const void* W1   = d_in[4];
  const void* b1   = d_in[5];
  const void* Wc0  = d_in[6];
  const void* bc0  = d_in[7];
  const void* Wc1  = d_in[8];
  const void* bc1  = d_in[9];
  const void* Wout = d_in[10];
  const void* bout = d_in[11];
  const void *bn1g = d_in[12], *bn1b = d_in[13], *bn1rm = d_in[14], *bn1rv = d_in[15];
  const void *bc0g = d_in[16], *bc0b = d_in[17], *bc0rm = d_in[18], *bc0rv = d_in[19];
  const void *bc1g = d_in[20], *bc1b = d_in[21], *bc1rm = d_in[22], *bc1rv = d_in[23];
  const void *bn2g = d_in[24], *bn2b = d_in[25], *bn2rm = d_in[26], *bn2rv = d_in[27];
  (void)in_sizes; (void)n_in; (void)out_size; (void)ws_size;

  char* w = (char*)d_ws;
  auto carve = [&](size_t bytes) {
    char* p = w;
    w += (bytes + 255) & ~(size_t)255;
    return p;
  };
  int*   flags  = (int*)  carve(256);
  float* dinv   = (float*)carve(sizeof(float) * NN);
  int*   cnt8   = (int*)  carve(sizeof(int) * 8 * NN);
  int*   indptr = (int*)  carve(sizeof(int) * (NN + 1));
  int*   bsum   = (int*)  carve(sizeof(int) * 256);
  int*   rank   = (int*)  carve(sizeof(int) * NE);
  int*   srcs   = (int*)  carve(sizeof(int) * NE);
  unsigned short* Wtb = (unsigned short*)carve(sizeof(short) * 90112);
  float* cvec   = (float*)carve(sizeof(float) * 448);
  unsigned short* xb  = (unsigned short*)carve(sizeof(short) * (size_t)NN * 128);
  unsigned short* hb  = (unsigned short*)carve(sizeof(short) * (size_t)NN * 128);
  unsigned short* rb0 = (unsigned short*)carve(sizeof(short) * (size_t)NN * 128);
  unsigned short* rb1 = (unsigned short*)carve(sizeof(short) * (size_t)NN * 128);
  unsigned short* rb2 = (unsigned short*)carve(sizeof(short) * (size_t)NN * 128);

  const int gN8 = (8 * NN + 255) / 256;
  const int gG = (NN + 63) / 64;         // 782
  const int gA2 = (NN + 3) / 4;          // agg128: 4 waves/block, 1 node/wave
  const int gA1 = (NN + 7) / 8;          // agg64out: 8 half-waves/block

  // 1: sniff + zero counters
  k_sniff<<<gN8, 256, 0, stream>>>(x, ei, flags, cnt8);
  // 2: edges-count || x-convert || W-prep || c-prep (all flag-dependent only)
  k_fuse_prep<<<GE + GX + GW + GC, 256, 0, stream>>>(
      ei, x, xb, rank, cnt8,
      W1, Wc0, Wc1, Wout, bn1g, bc0g, bc1g, bn2g,
      bn1b, bc0b, bc1b, bn2b, bn1rm, bc0rm, bc1rm, bn2rm,
      bn1rv, bc0rv, bc1rv, bn2rv, Wtb, cvec, flags);
  // 3-4: scan
  k_scan1<<<NB, 256, 0, stream>>>(cnt8, indptr, bsum, dinv, NN);
  k_scan23<<<NB, 256, 0, stream>>>(indptr, bsum, NN, NB);

  const size_t offO  = 0;
  const size_t offR0 = (size_t)NN * 64;
  const size_t offR1 = offR0 + (size_t)NN * 128;
  const size_t offR2 = offR1 + (size_t)NN * 128;
  unsigned short* d0 = (unsigned short*)d_out;   // bf16 view of regions

  // 5: CSR fill || GEMM L1 (independent; GEMM hides under scatter)
  k_fill_gemm1<<<GE + gG, 256, 0, stream>>>(
      ei, rank, indptr, cnt8, srcs,
      xb, (const unsigned short*)x, Wtb + 0, cvec + 0, dinv, hb, flags);
  // 6: agg L1 -> r0
  k_agg128<true><<<gA2, 256, 0, stream>>>(hb, indptr, srcs, dinv, b1, d_out, offR0, rb0, flags);

  // 7-8: L2
  k_gemm_mfma<128, 128><<<gG, 256, 0, stream>>>(
      rb0, nullptr, nullptr, d0 + offR0, nullptr, nullptr, Wtb + 16384, cvec + 128, dinv, hb, flags);
  k_agg128<true><<<gA2, 256, 0, stream>>>(hb, indptr, srcs, dinv, bc0, d_out, offR1, rb1, flags);

  // 9-10: L3
  k_gemm_mfma<128, 256><<<gG, 256, 0, stream>>>(
      rb0, rb1, nullptr, d0 + offR0, d0 + offR1, nullptr, Wtb + 32768, cvec + 256, dinv, hb, flags);
  k_agg128<true><<<gA2, 256, 0, stream>>>(hb, indptr, srcs, dinv, bc1, d_out, offR2, rb2, flags);

  // 11-12: L4
  k_gemm_mfma<64, 384><<<gG, 256, 0, stream>>>(
      rb0, rb1, rb2, d0 + offR0, d0 + offR1, d0 + offR2, Wtb + 65536, cvec + 384, dinv, hb, flags);
  k_agg64out<<<gA1, 256, 0, stream>>>(hb, indptr, srcs, dinv, bout, d_out, flags);
}